// Round 1
// baseline (231.157 us; speedup 1.0000x reference)
//
#include <hip/hip_runtime.h>

#define K_STEPS 10

__global__ __launch_bounds__(448)
void pde_fused(const float* __restrict__ x,
               const float* __restrict__ conv_w,
               const float* __restrict__ conv_b,
               const float* __restrict__ bn_s,
               const float* __restrict__ bn_b,
               const float* __restrict__ bn_m,
               const float* __restrict__ bn_v,
               float* __restrict__ out,
               int C)
{
    const float DTc = 0.2f, EPSc = 1e-5f;
    const int plane = blockIdx.x;        // b*C + c
    const int ch = plane % C;
    const int tid = threadIdx.x;
    const size_t base = (size_t)plane * 3136;

    // xs: [58][58] zero-padded x tile (13456 B). hbB aliases xs (dead after setup).
    __shared__ float smem[3364 + 3136];
    float* xs  = smem;
    float* hbA = smem + 3364;   // [56][56]
    float* hbB = smem;          // [56][56], aliases xs

    // ---- stage x into padded LDS (coalesced global loads) ----
    for (int i = tid; i < 3364; i += 448) xs[i] = 0.0f;
    __syncthreads();
    float xv[7];
    #pragma unroll
    for (int k = 0; k < 7; ++k) xv[k] = x[base + tid + k * 448];
    #pragma unroll
    for (int k = 0; k < 7; ++k) {
        int idx = tid + k * 448;
        int rr = idx / 56, cc = idx - rr * 56;
        xs[(rr + 1) * 58 + (cc + 1)] = xv[k];
    }
    __syncthreads();

    // ---- per-channel uniforms (block-uniform addresses -> scalar loads) ----
    float wj[4][9], cbj[4];
    #pragma unroll
    for (int j = 0; j < 4; ++j) {
        #pragma unroll
        for (int t = 0; t < 9; ++t) wj[j][t] = conv_w[(j * C + ch) * 9 + t];
        cbj[j] = conv_b[j * C + ch];
    }
    float g[5], be[5];
    #pragma unroll
    for (int j = 0; j < 5; ++j) {
        float inv = bn_s[j * C + ch] * rsqrtf(bn_v[j * C + ch] + EPSc);
        g[j]  = inv;
        be[j] = bn_b[j * C + ch] - bn_m[j * C + ch] * inv;
    }

    // ---- this thread's 1x7 chunk: row r, cols c0..c0+6 ----
    const int r  = tid >> 3;
    const int c0 = (tid & 7) * 7;

    // conv window: rows r..r+2, cols c0..c0+8 (padded coords)
    float win[3][9];
    #pragma unroll
    for (int dr = 0; dr < 3; ++dr)
        #pragma unroll
        for (int dc = 0; dc < 9; ++dc)
            win[dr][dc] = xs[(r + dr) * 58 + c0 + dc];

    // coefficient planes: h' = C0*h + Cxm*up + Cxp*dn + Cym*left + Cyp*right + F
    float h[7], F[7], C0[7], Cxp[7], Cxm[7], Cyp[7], Cym[7];
    #pragma unroll
    for (int i = 0; i < 7; ++i) {
        float a0 = cbj[0], a1 = cbj[1], a2 = cbj[2], a3 = cbj[3];
        #pragma unroll
        for (int dr = 0; dr < 3; ++dr)
            #pragma unroll
            for (int dc = 0; dc < 3; ++dc) {
                float xw = win[dr][i + dc];
                a0 = fmaf(xw, wj[0][dr * 3 + dc], a0);
                a1 = fmaf(xw, wj[1][dr * 3 + dc], a1);
                a2 = fmaf(xw, wj[2][dr * 3 + dc], a2);
                a3 = fmaf(xw, wj[3][dr * 3 + dc], a3);
            }
        float uu  = fmaxf(fmaf(a0, g[0], be[0]), 0.0f);   // relu(bn0)
        float vv  = fmaxf(fmaf(a1, g[1], be[1]), 0.0f);   // relu(bn1)
        float z2  = fmaf(a2, g[2], be[2]);
        float z3  = fmaf(a3, g[3], be[3]);
        float Dxv = 1.0f / (1.0f + __expf(-z2));          // sigmoid(bn2), CDX=1
        float Dyv = 1.0f / (1.0f + __expf(-z3));          // sigmoid(bn3), CDY=1
        float A = DTc * Dxv, Bv = DTc * Dyv;
        float U = 0.5f * DTc * uu, V = 0.5f * DTc * vv;
        float hv = win[1][i + 1];                         // x at (r, c0+i)
        h[i]   = hv;
        F[i]   = DTc * hv;
        C0[i]  = 1.0f - 2.0f * A - 2.0f * Bv;
        Cxp[i] = A + U;   Cxm[i] = A - U;                 // row+1 / row-1 (axis 2)
        Cyp[i] = Bv + V;  Cym[i] = Bv - V;                // col+1 / col-1 (axis 3)
    }

    // initial h into buffer A
    #pragma unroll
    for (int i = 0; i < 7; ++i) hbA[r * 56 + c0 + i] = h[i];
    __syncthreads();

    // periodic-wrap neighbor indices (jnp.roll semantics)
    const int rm = (r == 0)  ? 55 : r - 1;
    const int rp = (r == 55) ? 0  : r + 1;
    const int lidx = r * 56 + ((c0 == 0)  ? 55 : c0 - 1);
    const int ridx = r * 56 + ((c0 == 49) ? 0  : c0 + 7);

    float* cur = hbA;
    float* nxt = hbB;
    #pragma unroll
    for (int s = 0; s < K_STEPS; ++s) {
        float up[7], dn[7];
        #pragma unroll
        for (int i = 0; i < 7; ++i) up[i] = cur[rm * 56 + c0 + i];
        #pragma unroll
        for (int i = 0; i < 7; ++i) dn[i] = cur[rp * 56 + c0 + i];
        float lf = cur[lidx];
        float rg = cur[ridx];
        float nh[7];
        #pragma unroll
        for (int i = 0; i < 7; ++i) {
            float hl = (i == 0) ? lf : h[i - 1];
            float hr = (i == 6) ? rg : h[i + 1];
            float t = fmaf(C0[i], h[i], F[i]);
            t = fmaf(Cxm[i], up[i], t);
            t = fmaf(Cxp[i], dn[i], t);
            t = fmaf(Cym[i], hl, t);
            t = fmaf(Cyp[i], hr, t);
            nh[i] = t;
        }
        #pragma unroll
        for (int i = 0; i < 7; ++i) nxt[r * 56 + c0 + i] = nh[i];
        #pragma unroll
        for (int i = 0; i < 7; ++i) h[i] = nh[i];
        __syncthreads();
        float* t2 = cur; cur = nxt; nxt = t2;
    }

    // ---- final bn4 + relu, coalesced store ----
    #pragma unroll
    for (int k = 0; k < 7; ++k) {
        int idx = tid + k * 448;
        float y = fmaf(cur[idx], g[4], be[4]);
        out[base + idx] = fmaxf(y, 0.0f);
    }
}

extern "C" void kernel_launch(void* const* d_in, const int* in_sizes, int n_in,
                              void* d_out, int out_size, void* d_ws, size_t ws_size,
                              hipStream_t stream) {
    const float* x  = (const float*)d_in[0];
    const float* cw = (const float*)d_in[1];
    const float* cb = (const float*)d_in[2];
    const float* bs = (const float*)d_in[3];
    const float* bb = (const float*)d_in[4];
    const float* bm = (const float*)d_in[5];
    const float* bv = (const float*)d_in[6];
    float* out = (float*)d_out;

    int C = in_sizes[2] / 4;            // conv_b is [4, C]
    int planes = in_sizes[0] / 3136;    // B*C planes of 56*56

    pde_fused<<<planes, 448, 0, stream>>>(x, cw, cb, bs, bb, bm, bv, out, C);
}